// Round 6
// baseline (275.980 us; speedup 1.0000x reference)
//
#include <hip/hip_runtime.h>
#include <hip/hip_bf16.h>
#include <math.h>

// Problem constants
#define BB   32
#define HH   40
#define WW   256
#define NF   40          // FREQ
#define H1N  36
#define W1N  252
#define KCNN 580608      // 64*36*252
#define NBLK2 1134       // k2 blocks (x4 waves = 4536 slices)
#define KPW2 128         // k per wave slice; 4536*128 == KCNN exactly

typedef __attribute__((ext_vector_type(8))) short bf16x8;   // 8 bf16 = 4 VGPRs
typedef __attribute__((ext_vector_type(4))) short bf16x4;   // 4 bf16 = 2 VGPRs
typedef __attribute__((ext_vector_type(4))) float f32x4;    // MFMA C/D

static __device__ __forceinline__ unsigned short f2bf(float v) {
    __hip_bfloat16 h = __float2bfloat16(v);
    return *(unsigned short*)&h;
}

static __device__ __forceinline__ bf16x8 packbf(float4 lo, float4 hi) {
    bf16x8 r;
    r[0] = (short)f2bf(lo.x); r[1] = (short)f2bf(lo.y);
    r[2] = (short)f2bf(lo.z); r[3] = (short)f2bf(lo.w);
    r[4] = (short)f2bf(hi.x); r[5] = (short)f2bf(hi.y);
    r[6] = (short)f2bf(hi.z); r[7] = (short)f2bf(hi.w);
    return r;
}

// ---------------- K0: weight prep + accumulator zeroing ----------------
// w1c [tap][c1][c0] bf16 (conv1 A); w0c [c0][k32 zero-pad] bf16 (conv0 A); gacc/done=0.
__global__ void k0_prep(const float* __restrict__ w1, const float* __restrict__ w0,
                        unsigned short* __restrict__ w1c, unsigned short* __restrict__ w0c,
                        float* __restrict__ gacc, unsigned int* __restrict__ done) {
    int o = blockIdx.x * 256 + threadIdx.x;   // 72*256 = 18432 = 9*64*32
    {
        int c0  = o & 31;
        int c1  = (o >> 5) & 63;
        int tap = o >> 11;                    // 0..8
        w1c[o] = f2bf(w1[(c1 * 32 + c0) * 9 + tap]);
    }
    if (blockIdx.x == 70) {
        for (int i = threadIdx.x; i < 1024; i += 256) {   // 32 c0 x 32 k
            int c0 = i >> 5, k = i & 31;
            w0c[i] = (k < 9) ? f2bf(w0[c0 * 9 + k]) : (unsigned short)0;
        }
    }
    if (blockIdx.x == 71) {
        for (int p = threadIdx.x; p < 1280; p += 256) gacc[p] = 0.0f;
        if (threadIdx.x == 0) *done = 0u;
    }
}

// ---------------- K1: fused conv0 + conv1, BOTH via bf16 MFMA -> x (bf16) ----------------
// grid (4 jt, 9 it, 32 b), block 256 (4 waves).
// Phase A: input tile -> LDS. Phase C: conv0 as 16x16x32 MFMA (K=32 zero-padded taps):
// B-frag built in-register from ins (quad0 = taps 0-7, quad1 = tap 8, quads 2-3 zero),
// A = w0c (global, L1-hot); D -> relu+bias+mask -> packed b64 writes to y0T[pos][c0 pad40].
// Phase D: conv1 = 9 tap-GEMMs K=32. Phase E: LDS-transpose coalesced store.
__global__ __launch_bounds__(256) void k1_conv(
        const float* __restrict__ inp, const unsigned short* __restrict__ w0c,
        const float* __restrict__ b0, const unsigned short* __restrict__ w1c,
        const float* __restrict__ b1, unsigned short* __restrict__ xbf) {
    __shared__ __align__(16) unsigned short smem[18432];   // 36864 B, aliased phases
    unsigned short* y0T = smem;                   // [pos<400][c0 pad40] bf16 (32000 B)
    float* ins = (float*)(smem + 16000);          // [8][68]+2 f32 (2184 B) at byte 32000
    unsigned short* xp = smem;                    // phase E: [256 rows][72] bf16

    const int jt = blockIdx.x;        // j0 = 64*jt
    const int it = blockIdx.y;        // i0 = 4*it
    const int b  = blockIdx.z;
    const int i0 = it * 4;
    const int j0 = jt * 64;
    const int tid = threadIdx.x;

    const int w    = tid >> 6;        // wave id
    const int lane = tid & 63;
    const int l15  = lane & 15;
    const int quad = lane >> 4;

    // ---- A: stage input rows i0..i0+7, cols j0..j0+67 (+2 pad) ----
    for (int s = tid; s < 546; s += 256) {
        int r = s / 68, c = s - r * 68;
        float v = 0.0f;
        if (r < 8 && (j0 + c) < WW) v = inp[(b * HH + i0 + r) * WW + j0 + c];
        ins[s] = v;
    }
    __syncthreads();

    // ---- C: conv0 MFMA. Wave w owns n-tiles {w, w+4, ...} of 25 (pos = l15+16*nt) ----
    {
        bf16x8 a0f = *(const bf16x8*)(w0c + (0 * 16 + l15) * 32 + quad * 8);
        bf16x8 a1f = *(const bf16x8*)(w0c + (1 * 16 + l15) * 32 + quad * 8);
        float bias0[2][4];
        #pragma unroll
        for (int mt = 0; mt < 2; ++mt)
            #pragma unroll
            for (int rg = 0; rg < 4; ++rg)
                bias0[mt][rg] = b0[mt * 16 + quad * 4 + rg];

        for (int nt = w; nt < 25; nt += 4) {
            const int pos  = l15 + 16 * nt;
            const int posc = (pos < 396) ? pos : 395;
            const int r    = posc / 66;
            const int col  = posc - r * 66;
            bf16x8 bfrag = (bf16x8){0, 0, 0, 0, 0, 0, 0, 0};
            if (quad == 0) {
                const float* p0 = ins + r * 68 + col;
                bfrag[0] = (short)f2bf(p0[0]);
                bfrag[1] = (short)f2bf(p0[1]);
                bfrag[2] = (short)f2bf(p0[2]);
                bfrag[3] = (short)f2bf(p0[68]);
                bfrag[4] = (short)f2bf(p0[69]);
                bfrag[5] = (short)f2bf(p0[70]);
                bfrag[6] = (short)f2bf(p0[136]);
                bfrag[7] = (short)f2bf(p0[137]);
            } else if (quad == 1) {
                bfrag[0] = (short)f2bf(ins[(r + 2) * 68 + col + 2]);
            }
            f32x4 d0 = (f32x4){0.f, 0.f, 0.f, 0.f};
            f32x4 d1 = (f32x4){0.f, 0.f, 0.f, 0.f};
            d0 = __builtin_amdgcn_mfma_f32_16x16x32_bf16(a0f, bfrag, d0, 0, 0, 0);
            d1 = __builtin_amdgcn_mfma_f32_16x16x32_bf16(a1f, bfrag, d1, 0, 0, 0);
            const bool valid = (j0 + col) < 254;
            if (pos < 396) {
                bf16x4 v0, v1;
                #pragma unroll
                for (int rg = 0; rg < 4; ++rg) {
                    float x0 = valid ? fmaxf(d0[rg] + bias0[0][rg], 0.0f) : 0.0f;
                    float x1 = valid ? fmaxf(d1[rg] + bias0[1][rg], 0.0f) : 0.0f;
                    v0[rg] = (short)f2bf(x0);
                    v1[rg] = (short)f2bf(x1);
                }
                *(bf16x4*)(y0T + pos * 40 +      quad * 4) = v0;
                *(bf16x4*)(y0T + pos * 40 + 16 + quad * 4) = v1;
            }
        }
    }
    __syncthreads();

    // ---- D: conv1, 9 tap-GEMMs K=32. A = w1c (L1-hot global), B = y0T (LDS) ----
    float biasr[4][4];
    #pragma unroll
    for (int mt = 0; mt < 4; ++mt)
        #pragma unroll
        for (int rg = 0; rg < 4; ++rg)
            biasr[mt][rg] = b1[mt * 16 + quad * 4 + rg];

    f32x4 acc[4][4];                  // [mt(ch)][nt(pos)]
    #pragma unroll
    for (int mt = 0; mt < 4; ++mt)
        #pragma unroll
        for (int nt = 0; nt < 4; ++nt)
            acc[mt][nt] = (f32x4){0.f, 0.f, 0.f, 0.f};

    #pragma unroll
    for (int ki = 0; ki < 3; ++ki) {
        #pragma unroll
        for (int kj = 0; kj < 3; ++kj) {
            const int tap = ki * 3 + kj;
            bf16x8 af[4], bfr[4];
            #pragma unroll
            for (int mt = 0; mt < 4; ++mt)
                af[mt] = *(const bf16x8*)(w1c + ((tap * 64 + mt * 16 + l15) * 32 + quad * 8));
            #pragma unroll
            for (int nt = 0; nt < 4; ++nt)
                bfr[nt] = *(const bf16x8*)(y0T + (((w + ki) * 66 + nt * 16 + l15 + kj) * 40 + quad * 8));
            #pragma unroll
            for (int mt = 0; mt < 4; ++mt)
                #pragma unroll
                for (int nt = 0; nt < 4; ++nt)
                    acc[mt][nt] = __builtin_amdgcn_mfma_f32_16x16x32_bf16(
                        af[mt], bfr[nt], acc[mt][nt], 0, 0, 0);
        }
    }
    __syncthreads();                  // y0T reads complete before xp overwrite

    // ---- E: relu(x+b1) -> LDS transpose -> coalesced stores ----
    #pragma unroll
    for (int nt = 0; nt < 4; ++nt) {
        const int j = nt * 16 + l15;
        #pragma unroll
        for (int mt = 0; mt < 4; ++mt) {
            #pragma unroll
            for (int rg = 0; rg < 4; ++rg) {
                const int c1 = mt * 16 + quad * 4 + rg;
                const float v = fmaxf(acc[mt][nt][rg] + biasr[mt][rg], 0.0f);
                xp[(c1 * 4 + w) * 72 + j] = f2bf(v);
            }
        }
    }
    __syncthreads();
    {
        const int chunk = tid & 7;
        const int rb    = tid >> 3;
        #pragma unroll
        for (int p = 0; p < 8; ++p) {
            const int rowid = rb + 32 * p;
            const int c1 = rowid >> 2, ci = rowid & 3;
            uint4 v = *(const uint4*)&xp[rowid * 72 + chunk * 8];
            const int gj = j0 + chunk * 8;
            unsigned short* gp = xbf + (size_t)b * KCNN
                               + (size_t)(c1 * H1N + i0 + ci) * W1N + gj;
            uint2 lo; lo.x = v.x; lo.y = v.y;
            if (gj + 8 <= W1N) {
                uint2 hi; hi.x = v.z; hi.y = v.w;
                *(uint2*)gp = lo;
                *(uint2*)(gp + 4) = hi;
            } else if (gj < W1N) {    // jt==3, chunk==7: shorts 248..251
                *(uint2*)gp = lo;
            }
        }
    }
}

// ---------------- K2: max-flight MFMA split-K GEMM + fused gate epilogue ----------------
// 1134 blocks x 4 waves; each wave owns a 128-k slice (4 chunks x 32). ALL 32 load
// instructions issued straight-line before any use -> ~128 VGPRs of live load dests
// the compiler cannot recycle -> one HBM-latency exposure per wave (round 5: nine,
// VGPR=56 showed the pipeline was serialized). Block reduce -> atomics; last block
// (done counter) computes sigmoid gates + wtd_mean.
__global__ __launch_bounds__(256) void k2_gemm(
        const unsigned short* __restrict__ xbf, const float* __restrict__ wr,
        const float* __restrict__ br, float* __restrict__ gacc,
        unsigned int* __restrict__ done, float* __restrict__ gates,
        float* __restrict__ out) {
    __shared__ float red[4][32][41];
    __shared__ unsigned int lastf;

    const int tid  = threadIdx.x;
    const int wv   = tid >> 6;
    const int lane = tid & 63;
    const int l15  = lane & 15;
    const int quad = lane >> 4;
    const size_t kw = (size_t)(blockIdx.x * 4 + wv) * KPW2;

    const unsigned short* ap0 = xbf + (size_t)l15 * KCNN + kw + quad * 8;
    const unsigned short* ap1 = ap0 + (size_t)16 * KCNN;
    const float* bp0 = wr + (size_t)l15 * KCNN + kw + quad * 8;
    const float* bp1 = bp0 + (size_t)16 * KCNN;
    const int r2 = (l15 < 8) ? (32 + l15) : 39;       // clamp; cols>=40 discarded
    const float* bp2 = wr + (size_t)r2 * KCNN + kw + quad * 8;

    bf16x8 A0[4], A1[4];
    float4 B[3][4][2];
    #pragma unroll
    for (int c = 0; c < 4; ++c) {
        const int o = c * 32;
        A0[c] = *(const bf16x8*)(ap0 + o);
        A1[c] = *(const bf16x8*)(ap1 + o);
        B[0][c][0] = *(const float4*)(bp0 + o); B[0][c][1] = *(const float4*)(bp0 + o + 4);
        B[1][c][0] = *(const float4*)(bp1 + o); B[1][c][1] = *(const float4*)(bp1 + o + 4);
        B[2][c][0] = *(const float4*)(bp2 + o); B[2][c][1] = *(const float4*)(bp2 + o + 4);
    }

    f32x4 acc[2][3];
    #pragma unroll
    for (int mt = 0; mt < 2; ++mt)
        #pragma unroll
        for (int nt = 0; nt < 3; ++nt)
            acc[mt][nt] = (f32x4){0.f, 0.f, 0.f, 0.f};

    #pragma unroll
    for (int c = 0; c < 4; ++c) {
        #pragma unroll
        for (int nt = 0; nt < 3; ++nt) {
            bf16x8 bfrag = packbf(B[nt][c][0], B[nt][c][1]);
            acc[0][nt] = __builtin_amdgcn_mfma_f32_16x16x32_bf16(A0[c], bfrag, acc[0][nt], 0, 0, 0);
            acc[1][nt] = __builtin_amdgcn_mfma_f32_16x16x32_bf16(A1[c], bfrag, acc[1][nt], 0, 0, 0);
        }
    }

    // ---- block reduce 4 waves -> atomics ----
    #pragma unroll
    for (int mt = 0; mt < 2; ++mt)
        #pragma unroll
        for (int nt = 0; nt < 3; ++nt)
            #pragma unroll
            for (int rg = 0; rg < 4; ++rg) {
                int bb = mt * 16 + quad * 4 + rg;
                int ff = nt * 16 + l15;
                if (ff < NF) red[wv][bb][ff] = acc[mt][nt][rg];
            }
    __syncthreads();
    for (int p = tid; p < 1280; p += 256) {
        int bb = p / 40, ff = p - bb * 40;
        atomicAdd(gacc + p, red[0][bb][ff] + red[1][bb][ff] + red[2][bb][ff] + red[3][bb][ff]);
    }
    __syncthreads();

    if (tid == 0) {
        __threadfence();              // release: our gacc adds visible before count
        lastf = (atomicAdd(done, 1u) == NBLK2 - 1) ? 1u : 0u;
    }
    __syncthreads();
    if (lastf) {                      // ---- fused k3: gates + wtd_mean ----
        __threadfence();              // acquire
        float part = 0.0f;
        for (int p = tid; p < 1280; p += 256) {
            float s = __hip_atomic_load(gacc + p, __ATOMIC_RELAXED, __HIP_MEMORY_SCOPE_AGENT);
            int f = p % 40;
            float g = 1.0f / (1.0f + __expf(-(s + br[f])));
            gates[p] = g;
            part += g * 2.0f * (float)(f + 1);
        }
        #pragma unroll
        for (int off = 32; off >= 1; off >>= 1) part += __shfl_xor(part, off);
        float* redf = (float*)red;
        if ((tid & 63) == 0) redf[tid >> 6] = part;
        __syncthreads();
        if (tid == 0)
            out[51200] = (redf[0] + redf[1] + redf[2] + redf[3]) * (1.0f / 1280.0f);
    }
}

// ---------------- K4: feats (inline) -> sin/cos projection -> mods ----------------
__global__ __launch_bounds__(320) void k4_mods(
        const float* __restrict__ inp, const float* __restrict__ wf,
        const float* __restrict__ bfp, const float* __restrict__ gates,
        float* __restrict__ out) {
    const int f = blockIdx.x, b = blockIdx.y;
    const int tid = threadIdx.x;
    const int h  = tid >> 3;
    const int wl = tid & 7;
    float wfv[5];
    #pragma unroll
    for (int t = 0; t < 5; ++t) wfv[t] = wf[t];
    const float bias = bfp[0];
    const float cph = 6.283185307179586f * (float)(f + 1) / 255.0f;
    const float* row = inp + (b * HH + h) * WW;
    float sa = 0.0f, ca = 0.0f;
    for (int m = 0; m < 32; ++m) {
        int w = wl + 8 * m;
        float feat = bias;
        #pragma unroll
        for (int d = -2; d <= 2; ++d) {
            int wc = w + d;
            if (wc >= 0 && wc < WW) feat = fmaf(row[wc], wfv[d + 2], feat);
        }
        float sv, cv;
        __sincosf(cph * (float)w, &sv, &cv);
        sa = fmaf(sv, feat, sa);
        ca = fmaf(cv, feat, ca);
    }
    #pragma unroll
    for (int off = 4; off >= 1; off >>= 1) {
        sa += __shfl_xor(sa, off, 8);
        ca += __shfl_xor(ca, off, 8);
    }
    if (wl == 0) {
        float mag = sqrtf(sa * sa + ca * ca) * (1.0f / 256.0f);
        out[b * 1600 + f * 40 + h] = mag * gates[b * 40 + f];
    }
}

extern "C" void kernel_launch(void* const* d_in, const int* in_sizes, int n_in,
                              void* d_out, int out_size, void* d_ws, size_t ws_size,
                              hipStream_t stream) {
    const float* inp = (const float*)d_in[0];
    const float* w0  = (const float*)d_in[1];
    const float* b0  = (const float*)d_in[2];
    const float* w1  = (const float*)d_in[3];
    const float* b1  = (const float*)d_in[4];
    const float* wf  = (const float*)d_in[5];
    const float* bf_ = (const float*)d_in[6];
    const float* wr  = (const float*)d_in[7];
    const float* br  = (const float*)d_in[8];
    float* out = (float*)d_out;

    char* ws = (char*)d_ws;
    unsigned short* xbf = (unsigned short*)ws;               // 37,158,912 B
    unsigned short* w1c = (unsigned short*)(ws + 37158912);  // 36,864 B
    unsigned short* w0c = (unsigned short*)(ws + 37195776);  // 2,048 B
    float* gacc  = (float*)(ws + 37197824);                  // 5,120 B
    float* gates = (float*)(ws + 37202944);                  // 5,120 B
    unsigned int* done = (unsigned int*)(ws + 37208064);     // 4 B

    k0_prep<<<72, 256, 0, stream>>>(w1, w0, w1c, w0c, gacc, done);
    k1_conv<<<dim3(4, 9, 32), 256, 0, stream>>>(inp, w0c, b0, w1c, b1, xbf);
    k2_gemm<<<NBLK2, 256, 0, stream>>>(xbf, wr, br, gacc, done, gates, out);
    k4_mods<<<dim3(40, 32), 320, 0, stream>>>(inp, wf, bf_, gates, out);
}

// Round 7
// 252.435 us; speedup vs baseline: 1.0933x; 1.0933x over previous
//
#include <hip/hip_runtime.h>
#include <hip/hip_bf16.h>
#include <math.h>

// Problem constants
#define BB   32
#define HH   40
#define WW   256
#define NF   40          // FREQ
#define H1N  36
#define W1N  252
#define KCNN 580608      // 64*36*252
#define NBLK2 504        // k2 blocks (x4 waves = 2016 slices)
#define KPW  288         // k per wave slice; 2016*288 == KCNN exactly
#define NREP 32          // gacc replicas (atomic fan-in sharding)

typedef __attribute__((ext_vector_type(8))) short bf16x8;   // 8 bf16 = 4 VGPRs
typedef __attribute__((ext_vector_type(4))) short bf16x4;   // 4 bf16 = 2 VGPRs
typedef __attribute__((ext_vector_type(4))) float f32x4;    // MFMA C/D

static __device__ __forceinline__ unsigned short f2bf(float v) {
    __hip_bfloat16 h = __float2bfloat16(v);
    return *(unsigned short*)&h;
}

static __device__ __forceinline__ bf16x8 packbf(float4 lo, float4 hi) {
    bf16x8 r;
    r[0] = (short)f2bf(lo.x); r[1] = (short)f2bf(lo.y);
    r[2] = (short)f2bf(lo.z); r[3] = (short)f2bf(lo.w);
    r[4] = (short)f2bf(hi.x); r[5] = (short)f2bf(hi.y);
    r[6] = (short)f2bf(hi.z); r[7] = (short)f2bf(hi.w);
    return r;
}

// ---------------- K0: weight prep + replica zeroing ----------------
// w1c [tap][c1][c0] bf16; w0c [c0][k32 pad] bf16; gaccR[32][1280]=0; done=0.
__global__ void k0_prep(const float* __restrict__ w1, const float* __restrict__ w0,
                        unsigned short* __restrict__ w1c, unsigned short* __restrict__ w0c,
                        float* __restrict__ gaccR, unsigned int* __restrict__ done) {
    int o = blockIdx.x * 256 + threadIdx.x;   // 72*256 = 18432 = 9*64*32
    {
        int c0  = o & 31;
        int c1  = (o >> 5) & 63;
        int tap = o >> 11;                    // 0..8
        w1c[o] = f2bf(w1[(c1 * 32 + c0) * 9 + tap]);
    }
    if (blockIdx.x >= 40) {                   // 32 blocks zero the 32 replicas
        int rep = blockIdx.x - 40;
        for (int p = threadIdx.x; p < 1280; p += 256) gaccR[rep * 1280 + p] = 0.0f;
    }
    if (blockIdx.x == 70) {
        for (int i = threadIdx.x; i < 1024; i += 256) {   // 32 c0 x 32 k
            int c0 = i >> 5, k = i & 31;
            w0c[i] = (k < 9) ? f2bf(w0[c0 * 9 + k]) : (unsigned short)0;
        }
    }
    if (blockIdx.x == 71 && threadIdx.x == 0) *done = 0u;
}

// ---------------- K1: fused conv0 + conv1, BOTH via bf16 MFMA -> x (bf16) ----------------
// grid (4 jt, 9 it, 32 b), block 256 (4 waves). (unchanged from round 6)
__global__ __launch_bounds__(256) void k1_conv(
        const float* __restrict__ inp, const unsigned short* __restrict__ w0c,
        const float* __restrict__ b0, const unsigned short* __restrict__ w1c,
        const float* __restrict__ b1, unsigned short* __restrict__ xbf) {
    __shared__ __align__(16) unsigned short smem[18432];   // 36864 B, aliased phases
    unsigned short* y0T = smem;                   // [pos<400][c0 pad40] bf16 (32000 B)
    float* ins = (float*)(smem + 16000);          // [8][68]+2 f32 at byte 32000
    unsigned short* xp = smem;                    // phase E: [256 rows][72] bf16

    const int jt = blockIdx.x;        // j0 = 64*jt
    const int it = blockIdx.y;        // i0 = 4*it
    const int b  = blockIdx.z;
    const int i0 = it * 4;
    const int j0 = jt * 64;
    const int tid = threadIdx.x;

    const int w    = tid >> 6;        // wave id
    const int lane = tid & 63;
    const int l15  = lane & 15;
    const int quad = lane >> 4;

    // ---- A: stage input rows i0..i0+7, cols j0..j0+67 (+2 pad) ----
    for (int s = tid; s < 546; s += 256) {
        int r = s / 68, c = s - r * 68;
        float v = 0.0f;
        if (r < 8 && (j0 + c) < WW) v = inp[(b * HH + i0 + r) * WW + j0 + c];
        ins[s] = v;
    }
    __syncthreads();

    // ---- C: conv0 MFMA (K=32 zero-padded taps) ----
    {
        bf16x8 a0f = *(const bf16x8*)(w0c + (0 * 16 + l15) * 32 + quad * 8);
        bf16x8 a1f = *(const bf16x8*)(w0c + (1 * 16 + l15) * 32 + quad * 8);
        float bias0[2][4];
        #pragma unroll
        for (int mt = 0; mt < 2; ++mt)
            #pragma unroll
            for (int rg = 0; rg < 4; ++rg)
                bias0[mt][rg] = b0[mt * 16 + quad * 4 + rg];

        for (int nt = w; nt < 25; nt += 4) {
            const int pos  = l15 + 16 * nt;
            const int posc = (pos < 396) ? pos : 395;
            const int r    = posc / 66;
            const int col  = posc - r * 66;
            bf16x8 bfrag = (bf16x8){0, 0, 0, 0, 0, 0, 0, 0};
            if (quad == 0) {
                const float* p0 = ins + r * 68 + col;
                bfrag[0] = (short)f2bf(p0[0]);
                bfrag[1] = (short)f2bf(p0[1]);
                bfrag[2] = (short)f2bf(p0[2]);
                bfrag[3] = (short)f2bf(p0[68]);
                bfrag[4] = (short)f2bf(p0[69]);
                bfrag[5] = (short)f2bf(p0[70]);
                bfrag[6] = (short)f2bf(p0[136]);
                bfrag[7] = (short)f2bf(p0[137]);
            } else if (quad == 1) {
                bfrag[0] = (short)f2bf(ins[(r + 2) * 68 + col + 2]);
            }
            f32x4 d0 = (f32x4){0.f, 0.f, 0.f, 0.f};
            f32x4 d1 = (f32x4){0.f, 0.f, 0.f, 0.f};
            d0 = __builtin_amdgcn_mfma_f32_16x16x32_bf16(a0f, bfrag, d0, 0, 0, 0);
            d1 = __builtin_amdgcn_mfma_f32_16x16x32_bf16(a1f, bfrag, d1, 0, 0, 0);
            const bool valid = (j0 + col) < 254;
            if (pos < 396) {
                bf16x4 v0, v1;
                #pragma unroll
                for (int rg = 0; rg < 4; ++rg) {
                    float x0 = valid ? fmaxf(d0[rg] + bias0[0][rg], 0.0f) : 0.0f;
                    float x1 = valid ? fmaxf(d1[rg] + bias0[1][rg], 0.0f) : 0.0f;
                    v0[rg] = (short)f2bf(x0);
                    v1[rg] = (short)f2bf(x1);
                }
                *(bf16x4*)(y0T + pos * 40 +      quad * 4) = v0;
                *(bf16x4*)(y0T + pos * 40 + 16 + quad * 4) = v1;
            }
        }
    }
    __syncthreads();

    // ---- D: conv1, 9 tap-GEMMs K=32 ----
    float biasr[4][4];
    #pragma unroll
    for (int mt = 0; mt < 4; ++mt)
        #pragma unroll
        for (int rg = 0; rg < 4; ++rg)
            biasr[mt][rg] = b1[mt * 16 + quad * 4 + rg];

    f32x4 acc[4][4];                  // [mt(ch)][nt(pos)]
    #pragma unroll
    for (int mt = 0; mt < 4; ++mt)
        #pragma unroll
        for (int nt = 0; nt < 4; ++nt)
            acc[mt][nt] = (f32x4){0.f, 0.f, 0.f, 0.f};

    #pragma unroll
    for (int ki = 0; ki < 3; ++ki) {
        #pragma unroll
        for (int kj = 0; kj < 3; ++kj) {
            const int tap = ki * 3 + kj;
            bf16x8 af[4], bfr[4];
            #pragma unroll
            for (int mt = 0; mt < 4; ++mt)
                af[mt] = *(const bf16x8*)(w1c + ((tap * 64 + mt * 16 + l15) * 32 + quad * 8));
            #pragma unroll
            for (int nt = 0; nt < 4; ++nt)
                bfr[nt] = *(const bf16x8*)(y0T + (((w + ki) * 66 + nt * 16 + l15 + kj) * 40 + quad * 8));
            #pragma unroll
            for (int mt = 0; mt < 4; ++mt)
                #pragma unroll
                for (int nt = 0; nt < 4; ++nt)
                    acc[mt][nt] = __builtin_amdgcn_mfma_f32_16x16x32_bf16(
                        af[mt], bfr[nt], acc[mt][nt], 0, 0, 0);
        }
    }
    __syncthreads();                  // y0T reads complete before xp overwrite

    // ---- E: relu(x+b1) -> LDS transpose -> coalesced stores ----
    #pragma unroll
    for (int nt = 0; nt < 4; ++nt) {
        const int j = nt * 16 + l15;
        #pragma unroll
        for (int mt = 0; mt < 4; ++mt) {
            #pragma unroll
            for (int rg = 0; rg < 4; ++rg) {
                const int c1 = mt * 16 + quad * 4 + rg;
                const float v = fmaxf(acc[mt][nt][rg] + biasr[mt][rg], 0.0f);
                xp[(c1 * 4 + w) * 72 + j] = f2bf(v);
            }
        }
    }
    __syncthreads();
    {
        const int chunk = tid & 7;
        const int rb    = tid >> 3;
        #pragma unroll
        for (int p = 0; p < 8; ++p) {
            const int rowid = rb + 32 * p;
            const int c1 = rowid >> 2, ci = rowid & 3;
            uint4 v = *(const uint4*)&xp[rowid * 72 + chunk * 8];
            const int gj = j0 + chunk * 8;
            unsigned short* gp = xbf + (size_t)b * KCNN
                               + (size_t)(c1 * H1N + i0 + ci) * W1N + gj;
            uint2 lo; lo.x = v.x; lo.y = v.y;
            if (gj + 8 <= W1N) {
                uint2 hi; hi.x = v.z; hi.y = v.w;
                *(uint2*)gp = lo;
                *(uint2*)(gp + 4) = hi;
            } else if (gj < W1N) {    // jt==3, chunk==7: shorts 248..251
                *(uint2*)gp = lo;
            }
        }
    }
}

// ---------------- K2: MFMA split-K GEMM, sharded atomic fan-in + fused gates ----------------
// 504 blocks x 4 waves; wave owns a 288-k slice (9 chunks x 32), 2-deep register
// pipeline (round-5 shell — its loads were fine; the 63 us was the single-gacc
// atomic chain: 504 serial RMWs/line. Now: 32 replicas -> ~16-deep chains, ~2 us).
__global__ __launch_bounds__(256) void k2_gemm(
        const unsigned short* __restrict__ xbf, const float* __restrict__ wr,
        const float* __restrict__ br, float* __restrict__ gaccR,
        unsigned int* __restrict__ done, float* __restrict__ gates,
        float* __restrict__ out) {
    __shared__ float red[4][32][41];
    __shared__ unsigned int lastf;

    const int tid  = threadIdx.x;
    const int wv   = tid >> 6;
    const int lane = tid & 63;
    const int l15  = lane & 15;
    const int quad = lane >> 4;
    const size_t kw = (size_t)(blockIdx.x * 4 + wv) * KPW;

    const unsigned short* ap0 = xbf + (size_t)l15 * KCNN + kw + quad * 8;
    const unsigned short* ap1 = ap0 + (size_t)16 * KCNN;
    const float* bp0 = wr + (size_t)l15 * KCNN + kw + quad * 8;
    const float* bp1 = bp0 + (size_t)16 * KCNN;
    const int r2 = (l15 < 8) ? (32 + l15) : 39;       // clamp; cols>=40 discarded
    const float* bp2 = wr + (size_t)r2 * KCNN + kw + quad * 8;

    f32x4 acc[2][3];
    #pragma unroll
    for (int mt = 0; mt < 2; ++mt)
        #pragma unroll
        for (int nt = 0; nt < 3; ++nt)
            acc[mt][nt] = (f32x4){0.f, 0.f, 0.f, 0.f};

    bf16x8 a0c, a1c, a0n, a1n;
    float4 bw[3][2], bwn[3][2];

    a0c = *(const bf16x8*)ap0;
    a1c = *(const bf16x8*)ap1;
    bw[0][0] = *(const float4*)bp0; bw[0][1] = *(const float4*)(bp0 + 4);
    bw[1][0] = *(const float4*)bp1; bw[1][1] = *(const float4*)(bp1 + 4);
    bw[2][0] = *(const float4*)bp2; bw[2][1] = *(const float4*)(bp2 + 4);

    for (int c = 0; c < 9; ++c) {
        if (c < 8) {                  // prefetch next chunk; overlaps MFMA below
            const int o2 = (c + 1) * 32;
            a0n = *(const bf16x8*)(ap0 + o2);
            a1n = *(const bf16x8*)(ap1 + o2);
            bwn[0][0] = *(const float4*)(bp0 + o2); bwn[0][1] = *(const float4*)(bp0 + o2 + 4);
            bwn[1][0] = *(const float4*)(bp1 + o2); bwn[1][1] = *(const float4*)(bp1 + o2 + 4);
            bwn[2][0] = *(const float4*)(bp2 + o2); bwn[2][1] = *(const float4*)(bp2 + o2 + 4);
        }
        #pragma unroll
        for (int nt = 0; nt < 3; ++nt) {
            bf16x8 bfrag = packbf(bw[nt][0], bw[nt][1]);
            acc[0][nt] = __builtin_amdgcn_mfma_f32_16x16x32_bf16(a0c, bfrag, acc[0][nt], 0, 0, 0);
            acc[1][nt] = __builtin_amdgcn_mfma_f32_16x16x32_bf16(a1c, bfrag, acc[1][nt], 0, 0, 0);
        }
        if (c < 8) {
            a0c = a0n; a1c = a1n;
            #pragma unroll
            for (int nt = 0; nt < 3; ++nt) { bw[nt][0] = bwn[nt][0]; bw[nt][1] = bwn[nt][1]; }
        }
    }

    // ---- block reduce 4 waves -> sharded atomics ----
    #pragma unroll
    for (int mt = 0; mt < 2; ++mt)
        #pragma unroll
        for (int nt = 0; nt < 3; ++nt)
            #pragma unroll
            for (int rg = 0; rg < 4; ++rg) {
                int bb = mt * 16 + quad * 4 + rg;
                int ff = nt * 16 + l15;
                if (ff < NF) red[wv][bb][ff] = acc[mt][nt][rg];
            }
    __syncthreads();
    float* grep = gaccR + (blockIdx.x & (NREP - 1)) * 1280;
    for (int p = tid; p < 1280; p += 256) {
        int bb = p / 40, ff = p - bb * 40;
        atomicAdd(grep + p, red[0][bb][ff] + red[1][bb][ff] + red[2][bb][ff] + red[3][bb][ff]);
    }
    __syncthreads();

    if (tid == 0) {
        __threadfence();              // release: our adds visible before count
        lastf = (atomicAdd(done, 1u) == NBLK2 - 1) ? 1u : 0u;
    }
    __syncthreads();
    if (lastf) {                      // ---- fused k3: gates + wtd_mean ----
        __threadfence();              // acquire
        float part = 0.0f;
        for (int p = tid; p < 1280; p += 256) {
            float s = 0.0f;
            #pragma unroll 4
            for (int r = 0; r < NREP; ++r)
                s += __hip_atomic_load(gaccR + r * 1280 + p,
                                       __ATOMIC_RELAXED, __HIP_MEMORY_SCOPE_AGENT);
            int f = p % 40;
            float g = 1.0f / (1.0f + __expf(-(s + br[f])));
            gates[p] = g;
            part += g * 2.0f * (float)(f + 1);
        }
        #pragma unroll
        for (int off = 32; off >= 1; off >>= 1) part += __shfl_xor(part, off);
        float* redf = (float*)red;
        if ((tid & 63) == 0) redf[tid >> 6] = part;
        __syncthreads();
        if (tid == 0)
            out[51200] = (redf[0] + redf[1] + redf[2] + redf[3]) * (1.0f / 1280.0f);
    }
}

// ---------------- K4: feats (inline) -> sin/cos projection -> mods ----------------
__global__ __launch_bounds__(320) void k4_mods(
        const float* __restrict__ inp, const float* __restrict__ wf,
        const float* __restrict__ bfp, const float* __restrict__ gates,
        float* __restrict__ out) {
    const int f = blockIdx.x, b = blockIdx.y;
    const int tid = threadIdx.x;
    const int h  = tid >> 3;
    const int wl = tid & 7;
    float wfv[5];
    #pragma unroll
    for (int t = 0; t < 5; ++t) wfv[t] = wf[t];
    const float bias = bfp[0];
    const float cph = 6.283185307179586f * (float)(f + 1) / 255.0f;
    const float* row = inp + (b * HH + h) * WW;
    float sa = 0.0f, ca = 0.0f;
    for (int m = 0; m < 32; ++m) {
        int w = wl + 8 * m;
        float feat = bias;
        #pragma unroll
        for (int d = -2; d <= 2; ++d) {
            int wc = w + d;
            if (wc >= 0 && wc < WW) feat = fmaf(row[wc], wfv[d + 2], feat);
        }
        float sv, cv;
        __sincosf(cph * (float)w, &sv, &cv);
        sa = fmaf(sv, feat, sa);
        ca = fmaf(cv, feat, ca);
    }
    #pragma unroll
    for (int off = 4; off >= 1; off >>= 1) {
        sa += __shfl_xor(sa, off, 8);
        ca += __shfl_xor(ca, off, 8);
    }
    if (wl == 0) {
        float mag = sqrtf(sa * sa + ca * ca) * (1.0f / 256.0f);
        out[b * 1600 + f * 40 + h] = mag * gates[b * 40 + f];
    }
}

extern "C" void kernel_launch(void* const* d_in, const int* in_sizes, int n_in,
                              void* d_out, int out_size, void* d_ws, size_t ws_size,
                              hipStream_t stream) {
    const float* inp = (const float*)d_in[0];
    const float* w0  = (const float*)d_in[1];
    const float* b0  = (const float*)d_in[2];
    const float* w1  = (const float*)d_in[3];
    const float* b1  = (const float*)d_in[4];
    const float* wf  = (const float*)d_in[5];
    const float* bf_ = (const float*)d_in[6];
    const float* wr  = (const float*)d_in[7];
    const float* br  = (const float*)d_in[8];
    float* out = (float*)d_out;

    char* ws = (char*)d_ws;
    unsigned short* xbf = (unsigned short*)ws;               // 37,158,912 B
    unsigned short* w1c = (unsigned short*)(ws + 37158912);  // 36,864 B
    unsigned short* w0c = (unsigned short*)(ws + 37195776);  // 2,048 B
    float* gaccR = (float*)(ws + 37197824);                  // 32*1280*4 = 163,840 B
    float* gates = (float*)(ws + 37361664);                  // 5,120 B
    unsigned int* done = (unsigned int*)(ws + 37366784);     // 4 B

    k0_prep<<<72, 256, 0, stream>>>(w1, w0, w1c, w0c, gaccR, done);
    k1_conv<<<dim3(4, 9, 32), 256, 0, stream>>>(inp, w0c, b0, w1c, b1, xbf);
    k2_gemm<<<NBLK2, 256, 0, stream>>>(xbf, wr, br, gaccR, done, gates, out);
    k4_mods<<<dim3(40, 32), 320, 0, stream>>>(inp, wf, bf_, gates, out);
}